// Round 3
// baseline (328.647 us; speedup 1.0000x reference)
//
#include <hip/hip_runtime.h>
#include <hip/hip_bf16.h>

// Problem constants
#define NB   16      // batch
#define NC   256     // C_FEAT
#define HF   80
#define WF   80
#define NPIX 6400    // HF*WF
#define ND   64      // C_ILL
#define NK   3       // experts
#define NKC  7       // k-chunks of 32 (192 (k,d) + 3 bias + pad)
#define NPB  400     // NPIX/16 pixel-blocks per batch image
#define A_G_STRIDE  (NKC * 4 * 512)             // 14336 elem per g tile

// Workspace layouts:
//  ZF: [b][pb=400][half=2][lane=64][8] f32   swizzled z_up fragments (26.2 MB)
//      lane=(q,l15): elem j = z_up[px=pb*16+l15][half*32 + q*8 + j]
//  PU: [b][pb=400][k=3][l15=16] f32          p_up per pixel (1.23 MB)
//  A2: [g=8][kc=7][mt=4][lane=64][8] bf16    packed expert weights (229 KB)

typedef __bf16 bf16;
typedef __bf16 bf16x8 __attribute__((ext_vector_type(8)));
typedef float  floatx4 __attribute__((ext_vector_type(4)));

// ---------------------------------------------------------------------------
// Kernel 1 (fused): blocks [0, NB*HF) do bilinear upsample -> swizzled ZF/PU;
// blocks [NB*HF, NB*HF+56) pack expert weights into swizzled A2.
// ---------------------------------------------------------------------------
__global__ __launch_bounds__(256) void prep_kernel(
    const float* __restrict__ Z, const float* __restrict__ P,
    const float* __restrict__ Wg, const float* __restrict__ bg,
    const float* __restrict__ Wb, const float* __restrict__ bb,
    float* __restrict__ ZF, float* __restrict__ PU, bf16* __restrict__ A2)
{
    __shared__ float z_up[WF][ND + 1];
    __shared__ float p_up[WF][NK];

    const int bid = blockIdx.x;
    const int t   = threadIdx.x;

    if (bid >= NB * HF) {
        // ---------------- pack_A path (proven) ----------------
        int i = (bid - NB * HF) * 256 + t;   // 0 .. 14335
        int lane = i & 63;
        int j2 = i >> 6;           // 0..223
        int mt = j2 & 3;
        int j3 = j2 >> 2;          // 0..55
        int kc = j3 % 7;
        int g  = j3 / 7;           // 0..7
        int l15 = lane & 15, q = lane >> 4;
        int cbase = (g >> 1) * 64 + (g & 1) * 32;
        int c = cbase + (mt & 1) * 16 + l15;
        const float* W    = (mt >= 2) ? Wb : Wg;
        const float* bias = (mt >= 2) ? bb : bg;
        int kd0 = kc * 32 + q * 8;

        bf16x8 v;
        if (kd0 < NK * ND) {
            int k = kd0 >> 6, d = kd0 & 63;
            const float* src = W + ((size_t)k * NC + c) * ND + d;
            #pragma unroll
            for (int j = 0; j < 8; ++j) v[j] = (bf16)src[j];
        } else if (kd0 == NK * ND) {
            #pragma unroll
            for (int j = 0; j < 8; ++j) v[j] = (bf16)0.0f;
            v[0] = (bf16)bias[0 * NC + c];
            v[1] = (bf16)bias[1 * NC + c];
            v[2] = (bf16)bias[2 * NC + c];
        } else {
            #pragma unroll
            for (int j = 0; j < 8; ++j) v[j] = (bf16)0.0f;
        }
        *reinterpret_cast<bf16x8*>(A2 + (size_t)i * 8) = v;
        return;
    }

    // ---------------- build_z path (proven) ----------------
    const int b   = bid / HF;
    const int h   = bid - b * HF;

    float srch = 0.5f * (float)h - 0.25f;
    float flh  = floorf(srch);
    float fh   = srch - flh;
    int h0 = (int)flh, h1 = h0 + 1;
    h0 = max(h0, 0); h1 = min(h1, 40 - 1);

    // phase 1a: z_up[w][d], 5120 entries, 20 per thread
    #pragma unroll 4
    for (int i = 0; i < 20; ++i) {
        int e = t + 256 * i;
        int d = e / WF;
        int w = e - d * WF;
        float srcw = 0.5f * (float)w - 0.25f;
        float flw  = floorf(srcw);
        float fw   = srcw - flw;
        int w0 = (int)flw, w1 = w0 + 1;
        w0 = max(w0, 0); w1 = min(w1, 40 - 1);
        const float* Zr = Z + (size_t)(b * ND + d) * (40 * 40);
        float z00 = Zr[h0 * 40 + w0], z01 = Zr[h0 * 40 + w1];
        float z10 = Zr[h1 * 40 + w0], z11 = Zr[h1 * 40 + w1];
        float zi0 = z00 + fw * (z01 - z00);
        float zi1 = z10 + fw * (z11 - z10);
        z_up[w][d] = zi0 + fh * (zi1 - zi0);
    }
    // phase 1b: p_up[w][k], 240 entries
    if (t < WF * NK) {
        int w = t / NK;
        int k = t - w * NK;
        float srcw = 0.5f * (float)w - 0.25f;
        float flw  = floorf(srcw);
        float fw   = srcw - flw;
        int w0 = (int)flw, w1 = w0 + 1;
        w0 = max(w0, 0); w1 = min(w1, 40 - 1);
        const float* Pr = P + (size_t)(b * NK + k) * (40 * 40);
        float p00 = Pr[h0 * 40 + w0], p01 = Pr[h0 * 40 + w1];
        float p10 = Pr[h1 * 40 + w0], p11 = Pr[h1 * 40 + w1];
        float pi0 = p00 + fw * (p01 - p00);
        float pi1 = p10 + fw * (p11 - p10);
        p_up[w][k] = pi0 + fh * (pi1 - pi0);
    }
    __syncthreads();

    // phase 2a: z fragments. 5 pb * 2 half * 64 lanes = 640 chunks of 32 B
    for (int i = t; i < 640; i += 256) {
        int lane = i & 63;
        int j2   = i >> 6;          // 0..9
        int half = j2 & 1;
        int pb_l = j2 >> 1;         // 0..4
        int l15 = lane & 15, q = lane >> 4;
        int w   = pb_l * 16 + l15;
        int d0  = half * 32 + q * 8;
        float* dst = ZF + ((((size_t)(b * NPB + h * 5 + pb_l)) * 2 + half) * 64 + lane) * 8;
        floatx4 v0, v1;
        #pragma unroll
        for (int j = 0; j < 4; ++j) { v0[j] = z_up[w][d0 + j]; v1[j] = z_up[w][d0 + 4 + j]; }
        *reinterpret_cast<floatx4*>(dst)     = v0;
        *reinterpret_cast<floatx4*>(dst + 4) = v1;
    }
    // phase 2b: p values. 5 pb * 3 k * 16 px = 240 floats
    if (t < 240) {
        int pb_l = t / 48;
        int rem  = t - pb_l * 48;
        int k    = rem >> 4;
        int l15  = rem & 15;
        PU[(((size_t)(b * NPB + h * 5 + pb_l)) * 3 + k) * 16 + l15] = p_up[pb_l * 16 + l15][k];
    }
}

// ---------------------------------------------------------------------------
// Kernel 2: GEMM (pixels x channels, K=224) + fused FiLM epilogue.
// Swapped-operand MFMA (D: row=pixel, col=channel) keeps the float4 epilogue.
// This round: register diet for occupancy.  R1/R2 ran at 176-188 unified regs
// (VGPR_Count + 64 AGPR) = 2 waves/SIMD, 18% occupancy, 75% dead-issue time.
// Dropped: 32-VGPR feat prefetch (bought nothing in R2) and the manual A
// double-buffer (the unrolled loop lets the scheduler pipeline A-loads).
// __launch_bounds__(256,3) caps unified alloc at 170 -> 3 waves/SIMD.
// ---------------------------------------------------------------------------
__global__ __launch_bounds__(256, 3) void gemm_film_kernel(
    const bf16* __restrict__ A2, const float* __restrict__ ZF,
    const float* __restrict__ PU,
    const float* __restrict__ feat, float* __restrict__ out)
{
    const int ntb = blockIdx.x;   // 0..49  pixel tile (128 px)
    const int ct  = blockIdx.y;   // 0..3   c tile (64 c)
    const int b   = blockIdx.z;   // 0..15
    const int tid  = threadIdx.x;
    const int lane = tid & 63;
    const int wv   = tid >> 6;
    const int mq   = wv & 1;
    const int nh   = wv >> 1;
    const int l15  = lane & 15;
    const int q    = lane >> 4;

    const int g     = ct * 2 + mq;        // A2 tile id
    const int cbase = ct * 64 + mq * 32;
    const int pb0   = ntb * 8 + nh * 4;   // first of 4 pixel-blocks
    const int pix0  = pb0 * 16;

    // ---- B-side data: 8 z-frags (f32) + 12 p scalars, all independent ----
    floatx4 zf[4][2][2];   // [nt][half][lo/hi]
    #pragma unroll
    for (int nt = 0; nt < 4; ++nt)
        #pragma unroll
        for (int hf = 0; hf < 2; ++hf) {
            const float* cp = ZF + ((((size_t)(b * NPB + pb0 + nt)) * 2 + hf) * 64 + lane) * 8;
            zf[nt][hf][0] = *reinterpret_cast<const floatx4*>(cp);
            zf[nt][hf][1] = *reinterpret_cast<const floatx4*>(cp + 4);
        }
    float pv[4][3];
    #pragma unroll
    for (int nt = 0; nt < 4; ++nt)
        #pragma unroll
        for (int k = 0; k < 3; ++k)
            pv[nt][k] = PU[(((size_t)(b * NPB + pb0 + nt)) * 3 + k) * 16 + l15];

    const bf16* aptr = A2 + (size_t)g * A_G_STRIDE + (size_t)lane * 8;

    floatx4 acc[4][4] = {};  // [mt: 0,1 gamma / 2,3 beta][nt]

    #pragma unroll
    for (int kc = 0; kc < NKC; ++kc) {
        // A fragments for this k-chunk (L2-resident; scheduler pipelines
        // these across the unrolled iterations within the register cap)
        bf16x8 af[4];
        #pragma unroll
        for (int mt = 0; mt < 4; ++mt)
            af[mt] = *reinterpret_cast<const bf16x8*>(aptr + kc * 2048 + mt * 512);

        // build zp fragments (A operand) in registers for this k-chunk
        bf16x8 bfr[4];
        if (kc < 6) {
            const int hf = kc & 1;       // which 32-wide d half
            const int k  = kc >> 1;      // expert index
            #pragma unroll
            for (int nt = 0; nt < 4; ++nt) {
                float p = pv[nt][k];
                #pragma unroll
                for (int j = 0; j < 4; ++j) {
                    bfr[nt][j]     = (bf16)(p * zf[nt][hf][0][j]);
                    bfr[nt][j + 4] = (bf16)(p * zf[nt][hf][1][j]);
                }
            }
        } else {  // kc == 6: bias chunk (kd 192..194 live in q==0 lanes only)
            #pragma unroll
            for (int nt = 0; nt < 4; ++nt) {
                #pragma unroll
                for (int j = 0; j < 8; ++j) bfr[nt][j] = (bf16)0.0f;
                if (q == 0) {
                    bfr[nt][0] = (bf16)pv[nt][0];
                    bfr[nt][1] = (bf16)pv[nt][1];
                    bfr[nt][2] = (bf16)pv[nt][2];
                }
            }
        }
        // SWAPPED operand order: D[row=pixel][col=c]
        #pragma unroll
        for (int mt = 0; mt < 4; ++mt)
            #pragma unroll
            for (int nt = 0; nt < 4; ++nt)
                acc[mt][nt] = __builtin_amdgcn_mfma_f32_16x16x32_bf16(
                    bfr[nt], af[mt], acc[mt][nt], 0, 0, 0);
    }

    // fused FiLM epilogue, fully float4: out = feat*(1+gamma) + beta
    // c = cbase + mt*16 + l15 ; pix = pix0 + nt*16 + q*4 .. +3
    const float* featb = feat + ((size_t)(b * NC + cbase + l15)) * NPIX + pix0 + q * 4;
    float* outb = out + ((size_t)(b * NC + cbase + l15)) * NPIX + pix0 + q * 4;
    #pragma unroll
    for (int mt = 0; mt < 2; ++mt) {
        #pragma unroll
        for (int nt = 0; nt < 4; ++nt) {
            floatx4 f = *reinterpret_cast<const floatx4*>(
                featb + (size_t)mt * 16 * NPIX + nt * 16);
            floatx4 ga = acc[mt][nt];
            floatx4 be = acc[mt + 2][nt];
            floatx4 o;
            #pragma unroll
            for (int j = 0; j < 4; ++j)
                o[j] = f[j] * (1.0f + ga[j]) + be[j];
            *reinterpret_cast<floatx4*>(outb + (size_t)mt * 16 * NPIX + nt * 16) = o;
        }
    }
}

// ---------------------------------------------------------------------------
extern "C" void kernel_launch(void* const* d_in, const int* in_sizes, int n_in,
                              void* d_out, int out_size, void* d_ws, size_t ws_size,
                              hipStream_t stream)
{
    (void)in_sizes; (void)n_in; (void)out_size; (void)ws_size;
    const float* feat = (const float*)d_in[0];
    const float* Z    = (const float*)d_in[1];
    const float* P    = (const float*)d_in[2];
    const float* Wg   = (const float*)d_in[3];
    const float* bg   = (const float*)d_in[4];
    const float* Wb   = (const float*)d_in[5];
    const float* bb   = (const float*)d_in[6];

    float* ZF = (float*)d_ws;                               // 26,214,400 B
    float* PU = ZF + (size_t)NB * NPB * 2 * 64 * 8;         // + 1,228,800 B
    bf16*  Apk = (bf16*)(PU + (size_t)NB * NPB * 3 * 16);   // + 229,376 B
    float* out = (float*)d_out;

    prep_kernel<<<NB * HF + 56, 256, 0, stream>>>(Z, P, Wg, bg, Wb, bb, ZF, PU, Apk);

    dim3 grid(NPIX / 128, NC / 64, NB);
    gemm_film_kernel<<<grid, 256, 0, stream>>>(Apk, ZF, PU, feat, out);
}

// Round 4
// 250.891 us; speedup vs baseline: 1.3099x; 1.3099x over previous
//
#include <hip/hip_runtime.h>
#include <hip/hip_bf16.h>

// Problem constants
#define NB   16      // batch
#define NC   256     // C_FEAT
#define HF   80
#define WF   80
#define NPIX 6400    // HF*WF
#define ND   64      // C_ILL
#define NK   3       // experts
#define NKC  7       // k-chunks of 32 (192 (k,d) + 3 bias + pad)
#define NPB  400     // NPIX/16 pixel-blocks per batch image
#define A_G_STRIDE  (NKC * 4 * 512)             // 14336 elem per g tile

// Workspace layouts:
//  ZF: [b][pb=400][half=2][lane=64][8] f32   swizzled z_up fragments (26.2 MB)
//      lane=(q,l15): elem j = z_up[px=pb*16+l15][half*32 + q*8 + j]
//  PU: [b][pb=400][k=3][l15=16] f32          p_up per pixel (1.23 MB)
//  A2: [g=8][kc=7][mt=4][lane=64][8] bf16    packed expert weights (229 KB)

typedef __bf16 bf16;
typedef __bf16 bf16x8 __attribute__((ext_vector_type(8)));
typedef float  floatx4 __attribute__((ext_vector_type(4)));

// ---------------------------------------------------------------------------
// Kernel 1 (fused): blocks [0, NB*HF) do bilinear upsample -> swizzled ZF/PU;
// blocks [NB*HF, NB*HF+56) pack expert weights into swizzled A2.
// ---------------------------------------------------------------------------
__global__ __launch_bounds__(256) void prep_kernel(
    const float* __restrict__ Z, const float* __restrict__ P,
    const float* __restrict__ Wg, const float* __restrict__ bg,
    const float* __restrict__ Wb, const float* __restrict__ bb,
    float* __restrict__ ZF, float* __restrict__ PU, bf16* __restrict__ A2)
{
    __shared__ float z_up[WF][ND + 1];
    __shared__ float p_up[WF][NK];

    const int bid = blockIdx.x;
    const int t   = threadIdx.x;

    if (bid >= NB * HF) {
        // ---------------- pack_A path (proven) ----------------
        int i = (bid - NB * HF) * 256 + t;   // 0 .. 14335
        int lane = i & 63;
        int j2 = i >> 6;           // 0..223
        int mt = j2 & 3;
        int j3 = j2 >> 2;          // 0..55
        int kc = j3 % 7;
        int g  = j3 / 7;           // 0..7
        int l15 = lane & 15, q = lane >> 4;
        int cbase = (g >> 1) * 64 + (g & 1) * 32;
        int c = cbase + (mt & 1) * 16 + l15;
        const float* W    = (mt >= 2) ? Wb : Wg;
        const float* bias = (mt >= 2) ? bb : bg;
        int kd0 = kc * 32 + q * 8;

        bf16x8 v;
        if (kd0 < NK * ND) {
            int k = kd0 >> 6, d = kd0 & 63;
            const float* src = W + ((size_t)k * NC + c) * ND + d;
            #pragma unroll
            for (int j = 0; j < 8; ++j) v[j] = (bf16)src[j];
        } else if (kd0 == NK * ND) {
            #pragma unroll
            for (int j = 0; j < 8; ++j) v[j] = (bf16)0.0f;
            v[0] = (bf16)bias[0 * NC + c];
            v[1] = (bf16)bias[1 * NC + c];
            v[2] = (bf16)bias[2 * NC + c];
        } else {
            #pragma unroll
            for (int j = 0; j < 8; ++j) v[j] = (bf16)0.0f;
        }
        *reinterpret_cast<bf16x8*>(A2 + (size_t)i * 8) = v;
        return;
    }

    // ---------------- build_z path (proven) ----------------
    const int b   = bid / HF;
    const int h   = bid - b * HF;

    float srch = 0.5f * (float)h - 0.25f;
    float flh  = floorf(srch);
    float fh   = srch - flh;
    int h0 = (int)flh, h1 = h0 + 1;
    h0 = max(h0, 0); h1 = min(h1, 40 - 1);

    // phase 1a: z_up[w][d], 5120 entries, 20 per thread
    #pragma unroll 4
    for (int i = 0; i < 20; ++i) {
        int e = t + 256 * i;
        int d = e / WF;
        int w = e - d * WF;
        float srcw = 0.5f * (float)w - 0.25f;
        float flw  = floorf(srcw);
        float fw   = srcw - flw;
        int w0 = (int)flw, w1 = w0 + 1;
        w0 = max(w0, 0); w1 = min(w1, 40 - 1);
        const float* Zr = Z + (size_t)(b * ND + d) * (40 * 40);
        float z00 = Zr[h0 * 40 + w0], z01 = Zr[h0 * 40 + w1];
        float z10 = Zr[h1 * 40 + w0], z11 = Zr[h1 * 40 + w1];
        float zi0 = z00 + fw * (z01 - z00);
        float zi1 = z10 + fw * (z11 - z10);
        z_up[w][d] = zi0 + fh * (zi1 - zi0);
    }
    // phase 1b: p_up[w][k], 240 entries
    if (t < WF * NK) {
        int w = t / NK;
        int k = t - w * NK;
        float srcw = 0.5f * (float)w - 0.25f;
        float flw  = floorf(srcw);
        float fw   = srcw - flw;
        int w0 = (int)flw, w1 = w0 + 1;
        w0 = max(w0, 0); w1 = min(w1, 40 - 1);
        const float* Pr = P + (size_t)(b * NK + k) * (40 * 40);
        float p00 = Pr[h0 * 40 + w0], p01 = Pr[h0 * 40 + w1];
        float p10 = Pr[h1 * 40 + w0], p11 = Pr[h1 * 40 + w1];
        float pi0 = p00 + fw * (p01 - p00);
        float pi1 = p10 + fw * (p11 - p10);
        p_up[w][k] = pi0 + fh * (pi1 - pi0);
    }
    __syncthreads();

    // phase 2a: z fragments. 5 pb * 2 half * 64 lanes = 640 chunks of 32 B
    for (int i = t; i < 640; i += 256) {
        int lane = i & 63;
        int j2   = i >> 6;          // 0..9
        int half = j2 & 1;
        int pb_l = j2 >> 1;         // 0..4
        int l15 = lane & 15, q = lane >> 4;
        int w   = pb_l * 16 + l15;
        int d0  = half * 32 + q * 8;
        float* dst = ZF + ((((size_t)(b * NPB + h * 5 + pb_l)) * 2 + half) * 64 + lane) * 8;
        floatx4 v0, v1;
        #pragma unroll
        for (int j = 0; j < 4; ++j) { v0[j] = z_up[w][d0 + j]; v1[j] = z_up[w][d0 + 4 + j]; }
        *reinterpret_cast<floatx4*>(dst)     = v0;
        *reinterpret_cast<floatx4*>(dst + 4) = v1;
    }
    // phase 2b: p values. 5 pb * 3 k * 16 px = 240 floats
    if (t < 240) {
        int pb_l = t / 48;
        int rem  = t - pb_l * 48;
        int k    = rem >> 4;
        int l15  = rem & 15;
        PU[(((size_t)(b * NPB + h * 5 + pb_l)) * 3 + k) * 16 + l15] = p_up[pb_l * 16 + l15][k];
    }
}

// ---------------------------------------------------------------------------
// Kernel 2: GEMM (pixels x channels, K=224) + fused FiLM epilogue.
// Swapped-operand MFMA (D: row=pixel, col=channel) -> float4 epilogue.
// R3 post-mortem: forcing 3 waves/SIMD via launch_bounds spilled ~40 regs to
// scratch (+390 MB HBM traffic, 2x slower).  This round the per-wave state
// is HALVED instead (nt: 4->2, block = 64 px, grid.x = 100): acc 64->32 AGPR,
// zf 32->16, pv 12->6.  Natural need ~100-115 unified regs < 128 => 4
// waves/SIMD with ZERO spill (launch_bounds(256,4) budget exceeds need).
// Gate: WRITE_SIZE must be back at ~102,400 KB, else the theory is dead.
// ---------------------------------------------------------------------------
__global__ __launch_bounds__(256, 4) void gemm_film_kernel(
    const bf16* __restrict__ A2, const float* __restrict__ ZF,
    const float* __restrict__ PU,
    const float* __restrict__ feat, float* __restrict__ out)
{
    const int ntb = blockIdx.x;   // 0..99  pixel tile (64 px)
    const int ct  = blockIdx.y;   // 0..3   c tile (64 c)
    const int b   = blockIdx.z;   // 0..15
    const int tid  = threadIdx.x;
    const int lane = tid & 63;
    const int wv   = tid >> 6;
    const int mq   = wv & 1;
    const int nh   = wv >> 1;
    const int l15  = lane & 15;
    const int q    = lane >> 4;

    const int g     = ct * 2 + mq;        // A2 tile id
    const int cbase = ct * 64 + mq * 32;
    const int pb0   = ntb * 4 + nh * 2;   // first of 2 pixel-blocks
    const int pix0  = pb0 * 16;

    // ---- B-side data: 4 z-frags (f32) + 6 p scalars, all independent ----
    floatx4 zf[2][2][2];   // [nt][half][lo/hi]
    #pragma unroll
    for (int nt = 0; nt < 2; ++nt)
        #pragma unroll
        for (int hf = 0; hf < 2; ++hf) {
            const float* cp = ZF + ((((size_t)(b * NPB + pb0 + nt)) * 2 + hf) * 64 + lane) * 8;
            zf[nt][hf][0] = *reinterpret_cast<const floatx4*>(cp);
            zf[nt][hf][1] = *reinterpret_cast<const floatx4*>(cp + 4);
        }
    float pv[2][3];
    #pragma unroll
    for (int nt = 0; nt < 2; ++nt)
        #pragma unroll
        for (int k = 0; k < 3; ++k)
            pv[nt][k] = PU[(((size_t)(b * NPB + pb0 + nt)) * 3 + k) * 16 + l15];

    const bf16* aptr = A2 + (size_t)g * A_G_STRIDE + (size_t)lane * 8;

    floatx4 acc[4][2] = {};  // [mt: 0,1 gamma / 2,3 beta][nt]

    #pragma unroll
    for (int kc = 0; kc < NKC; ++kc) {
        // A fragments for this k-chunk (L2-resident)
        bf16x8 af[4];
        #pragma unroll
        for (int mt = 0; mt < 4; ++mt)
            af[mt] = *reinterpret_cast<const bf16x8*>(aptr + kc * 2048 + mt * 512);

        // build zp fragments (MFMA A operand) in registers for this k-chunk
        bf16x8 bfr[2];
        if (kc < 6) {
            const int hf = kc & 1;       // which 32-wide d half
            const int k  = kc >> 1;      // expert index
            #pragma unroll
            for (int nt = 0; nt < 2; ++nt) {
                float p = pv[nt][k];
                #pragma unroll
                for (int j = 0; j < 4; ++j) {
                    bfr[nt][j]     = (bf16)(p * zf[nt][hf][0][j]);
                    bfr[nt][j + 4] = (bf16)(p * zf[nt][hf][1][j]);
                }
            }
        } else {  // kc == 6: bias chunk (kd 192..194 live in q==0 lanes only)
            #pragma unroll
            for (int nt = 0; nt < 2; ++nt) {
                #pragma unroll
                for (int j = 0; j < 8; ++j) bfr[nt][j] = (bf16)0.0f;
                if (q == 0) {
                    bfr[nt][0] = (bf16)pv[nt][0];
                    bfr[nt][1] = (bf16)pv[nt][1];
                    bfr[nt][2] = (bf16)pv[nt][2];
                }
            }
        }
        // SWAPPED operand order: D[row=pixel][col=c]
        #pragma unroll
        for (int mt = 0; mt < 4; ++mt)
            #pragma unroll
            for (int nt = 0; nt < 2; ++nt)
                acc[mt][nt] = __builtin_amdgcn_mfma_f32_16x16x32_bf16(
                    bfr[nt], af[mt], acc[mt][nt], 0, 0, 0);
    }

    // fused FiLM epilogue, fully float4: out = feat*(1+gamma) + beta
    // c = cbase + mt*16 + l15 ; pix = pix0 + nt*16 + q*4 .. +3
    const float* featb = feat + ((size_t)(b * NC + cbase + l15)) * NPIX + pix0 + q * 4;
    float* outb = out + ((size_t)(b * NC + cbase + l15)) * NPIX + pix0 + q * 4;
    #pragma unroll
    for (int mt = 0; mt < 2; ++mt) {
        #pragma unroll
        for (int nt = 0; nt < 2; ++nt) {
            floatx4 f = *reinterpret_cast<const floatx4*>(
                featb + (size_t)mt * 16 * NPIX + nt * 16);
            floatx4 ga = acc[mt][nt];
            floatx4 be = acc[mt + 2][nt];
            floatx4 o;
            #pragma unroll
            for (int j = 0; j < 4; ++j)
                o[j] = f[j] * (1.0f + ga[j]) + be[j];
            *reinterpret_cast<floatx4*>(outb + (size_t)mt * 16 * NPIX + nt * 16) = o;
        }
    }
}

// ---------------------------------------------------------------------------
extern "C" void kernel_launch(void* const* d_in, const int* in_sizes, int n_in,
                              void* d_out, int out_size, void* d_ws, size_t ws_size,
                              hipStream_t stream)
{
    (void)in_sizes; (void)n_in; (void)out_size; (void)ws_size;
    const float* feat = (const float*)d_in[0];
    const float* Z    = (const float*)d_in[1];
    const float* P    = (const float*)d_in[2];
    const float* Wg   = (const float*)d_in[3];
    const float* bg   = (const float*)d_in[4];
    const float* Wb   = (const float*)d_in[5];
    const float* bb   = (const float*)d_in[6];

    float* ZF = (float*)d_ws;                               // 26,214,400 B
    float* PU = ZF + (size_t)NB * NPB * 2 * 64 * 8;         // + 1,228,800 B
    bf16*  Apk = (bf16*)(PU + (size_t)NB * NPB * 3 * 16);   // + 229,376 B
    float* out = (float*)d_out;

    prep_kernel<<<NB * HF + 56, 256, 0, stream>>>(Z, P, Wg, bg, Wb, bb, ZF, PU, Apk);

    dim3 grid(NPIX / 64, NC / 64, NB);
    gemm_film_kernel<<<grid, 256, 0, stream>>>(Apk, ZF, PU, feat, out);
}

// Round 5
// 232.981 us; speedup vs baseline: 1.4106x; 1.0769x over previous
//
#include <hip/hip_runtime.h>
#include <hip/hip_bf16.h>

// Problem constants
#define NB   16      // batch
#define NC   256     // C_FEAT
#define HF   80
#define WF   80
#define NPIX 6400    // HF*WF
#define ND   64      // C_ILL
#define NK   3       // experts
#define NKC  7       // k-chunks of 32 (192 (k,d) + 3 bias + pad)
#define NPB  400     // NPIX/16 pixel-blocks per batch image
#define A_G_STRIDE  (NKC * 4 * 512)             // 14336 elem per g tile

// Workspace layouts:
//  ZF: [b][pb=400][half=2][lane=64][8] f32   swizzled z_up fragments (26.2 MB)
//      lane=(q,l15): elem j = z_up[px=pb*16+l15][half*32 + q*8 + j]
//  PU: [b][pb=400][k=3][l15=16] f32          p_up per pixel (1.23 MB)
//  A2: [g=8][kc=7][mt=4][lane=64][8] bf16    packed expert weights (229 KB)

typedef __bf16 bf16;
typedef __bf16 bf16x8 __attribute__((ext_vector_type(8)));
typedef float  floatx4 __attribute__((ext_vector_type(4)));

#define GLOBAL_AS __attribute__((address_space(1)))
#define LDS_AS    __attribute__((address_space(3)))

// ---------------------------------------------------------------------------
// Kernel 1 (fused): blocks [0, NB*HF) do bilinear upsample -> swizzled ZF/PU;
// blocks [NB*HF, NB*HF+56) pack expert weights into swizzled A2.
// ---------------------------------------------------------------------------
__global__ __launch_bounds__(256) void prep_kernel(
    const float* __restrict__ Z, const float* __restrict__ P,
    const float* __restrict__ Wg, const float* __restrict__ bg,
    const float* __restrict__ Wb, const float* __restrict__ bb,
    float* __restrict__ ZF, float* __restrict__ PU, bf16* __restrict__ A2)
{
    __shared__ float z_up[WF][ND + 1];
    __shared__ float p_up[WF][NK];

    const int bid = blockIdx.x;
    const int t   = threadIdx.x;

    if (bid >= NB * HF) {
        // ---------------- pack_A path (proven) ----------------
        int i = (bid - NB * HF) * 256 + t;   // 0 .. 14335
        int lane = i & 63;
        int j2 = i >> 6;           // 0..223
        int mt = j2 & 3;
        int j3 = j2 >> 2;          // 0..55
        int kc = j3 % 7;
        int g  = j3 / 7;           // 0..7
        int l15 = lane & 15, q = lane >> 4;
        int cbase = (g >> 1) * 64 + (g & 1) * 32;
        int c = cbase + (mt & 1) * 16 + l15;
        const float* W    = (mt >= 2) ? Wb : Wg;
        const float* bias = (mt >= 2) ? bb : bg;
        int kd0 = kc * 32 + q * 8;

        bf16x8 v;
        if (kd0 < NK * ND) {
            int k = kd0 >> 6, d = kd0 & 63;
            const float* src = W + ((size_t)k * NC + c) * ND + d;
            #pragma unroll
            for (int j = 0; j < 8; ++j) v[j] = (bf16)src[j];
        } else if (kd0 == NK * ND) {
            #pragma unroll
            for (int j = 0; j < 8; ++j) v[j] = (bf16)0.0f;
            v[0] = (bf16)bias[0 * NC + c];
            v[1] = (bf16)bias[1 * NC + c];
            v[2] = (bf16)bias[2 * NC + c];
        } else {
            #pragma unroll
            for (int j = 0; j < 8; ++j) v[j] = (bf16)0.0f;
        }
        *reinterpret_cast<bf16x8*>(A2 + (size_t)i * 8) = v;
        return;
    }

    // ---------------- build_z path (proven) ----------------
    const int b   = bid / HF;
    const int h   = bid - b * HF;

    float srch = 0.5f * (float)h - 0.25f;
    float flh  = floorf(srch);
    float fh   = srch - flh;
    int h0 = (int)flh, h1 = h0 + 1;
    h0 = max(h0, 0); h1 = min(h1, 40 - 1);

    // phase 1a: z_up[w][d], 5120 entries, 20 per thread
    #pragma unroll 4
    for (int i = 0; i < 20; ++i) {
        int e = t + 256 * i;
        int d = e / WF;
        int w = e - d * WF;
        float srcw = 0.5f * (float)w - 0.25f;
        float flw  = floorf(srcw);
        float fw   = srcw - flw;
        int w0 = (int)flw, w1 = w0 + 1;
        w0 = max(w0, 0); w1 = min(w1, 40 - 1);
        const float* Zr = Z + (size_t)(b * ND + d) * (40 * 40);
        float z00 = Zr[h0 * 40 + w0], z01 = Zr[h0 * 40 + w1];
        float z10 = Zr[h1 * 40 + w0], z11 = Zr[h1 * 40 + w1];
        float zi0 = z00 + fw * (z01 - z00);
        float zi1 = z10 + fw * (z11 - z10);
        z_up[w][d] = zi0 + fh * (zi1 - zi0);
    }
    // phase 1b: p_up[w][k], 240 entries
    if (t < WF * NK) {
        int w = t / NK;
        int k = t - w * NK;
        float srcw = 0.5f * (float)w - 0.25f;
        float flw  = floorf(srcw);
        float fw   = srcw - flw;
        int w0 = (int)flw, w1 = w0 + 1;
        w0 = max(w0, 0); w1 = min(w1, 40 - 1);
        const float* Pr = P + (size_t)(b * NK + k) * (40 * 40);
        float p00 = Pr[h0 * 40 + w0], p01 = Pr[h0 * 40 + w1];
        float p10 = Pr[h1 * 40 + w0], p11 = Pr[h1 * 40 + w1];
        float pi0 = p00 + fw * (p01 - p00);
        float pi1 = p10 + fw * (p11 - p10);
        p_up[w][k] = pi0 + fh * (pi1 - pi0);
    }
    __syncthreads();

    // phase 2a: z fragments. 5 pb * 2 half * 64 lanes = 640 chunks of 32 B
    for (int i = t; i < 640; i += 256) {
        int lane = i & 63;
        int j2   = i >> 6;          // 0..9
        int half = j2 & 1;
        int pb_l = j2 >> 1;         // 0..4
        int l15 = lane & 15, q = lane >> 4;
        int w   = pb_l * 16 + l15;
        int d0  = half * 32 + q * 8;
        float* dst = ZF + ((((size_t)(b * NPB + h * 5 + pb_l)) * 2 + half) * 64 + lane) * 8;
        floatx4 v0, v1;
        #pragma unroll
        for (int j = 0; j < 4; ++j) { v0[j] = z_up[w][d0 + j]; v1[j] = z_up[w][d0 + 4 + j]; }
        *reinterpret_cast<floatx4*>(dst)     = v0;
        *reinterpret_cast<floatx4*>(dst + 4) = v1;
    }
    // phase 2b: p values. 5 pb * 3 k * 16 px = 240 floats
    if (t < 240) {
        int pb_l = t / 48;
        int rem  = t - pb_l * 48;
        int k    = rem >> 4;
        int l15  = rem & 15;
        PU[(((size_t)(b * NPB + h * 5 + pb_l)) * 3 + k) * 16 + l15] = p_up[pb_l * 16 + l15][k];
    }
}

// ---------------------------------------------------------------------------
// Kernel 2: GEMM (pixels x channels, K=224) + fused FiLM epilogue.
// R4 post-mortem: per-wave lifetime is invariant (~25k cy) across occupancy
// changes -> bound by the per-wave serial chain of A-fragment L2 loads in the
// k-loop.  This round A is staged into LDS ONCE PER BLOCK via
// global_load_lds (zero VGPR, wave-uniform dest + lane*16 = exactly our A2
// chunk layout); the k-loop becomes VMEM-free (ds_read_b128 only, ~120cy,
// compiler-pipelined).  Block = 4 waves sharing ONE g tile: 256 px x 32 c,
// grid (25, 8, 16).  Per-wave shape (nt=4, 64px) kept from R2 (best known).
// No min-waves forcing (R3 lesson: forced caps spill).
// ---------------------------------------------------------------------------
__global__ __launch_bounds__(256) void gemm_film_kernel(
    const bf16* __restrict__ A2, const float* __restrict__ ZF,
    const float* __restrict__ PU,
    const float* __restrict__ feat, float* __restrict__ out)
{
    __shared__ __attribute__((aligned(16))) bf16 Alds[28 * 512];  // 28 KB

    const int ntb = blockIdx.x;   // 0..24  pixel tile (256 px)
    const int g   = blockIdx.y;   // 0..7   c tile (32 c)
    const int b   = blockIdx.z;   // 0..15
    const int tid  = threadIdx.x;
    const int lane = tid & 63;
    const int nh   = tid >> 6;    // wave id = pixel sub-tile
    const int l15  = lane & 15;
    const int q    = lane >> 4;

    const int cbase = (g >> 1) * 64 + (g & 1) * 32;
    const int pb0   = ntb * 16 + nh * 4;   // first of 4 pixel-blocks
    const int pix0  = pb0 * 16;

    // ---- stage A g-tile (28 KB) into LDS: 7 chunks of 1 KB per wave ----
    {
        const bf16* gA = A2 + (size_t)g * A_G_STRIDE;
        #pragma unroll
        for (int j7 = 0; j7 < 7; ++j7) {
            int j = nh * 7 + j7;   // chunk 0..27, wave-uniform
            __builtin_amdgcn_global_load_lds(
                (const GLOBAL_AS void*)(gA + (size_t)j * 512 + lane * 8),
                (LDS_AS void*)(&Alds[j * 512]), 16, 0, 0);
        }
    }

    // ---- B-side data: 8 z-frags (f32) + 12 p scalars, all independent ----
    floatx4 zf[4][2][2];   // [nt][half][lo/hi]
    #pragma unroll
    for (int nt = 0; nt < 4; ++nt)
        #pragma unroll
        for (int hf = 0; hf < 2; ++hf) {
            const float* cp = ZF + ((((size_t)(b * NPB + pb0 + nt)) * 2 + hf) * 64 + lane) * 8;
            zf[nt][hf][0] = *reinterpret_cast<const floatx4*>(cp);
            zf[nt][hf][1] = *reinterpret_cast<const floatx4*>(cp + 4);
        }
    float pv[4][3];
    #pragma unroll
    for (int nt = 0; nt < 4; ++nt)
        #pragma unroll
        for (int k = 0; k < 3; ++k)
            pv[nt][k] = PU[(((size_t)(b * NPB + pb0 + nt)) * 3 + k) * 16 + l15];

    __syncthreads();   // A staged (drains vmcnt) + visible to all waves

    floatx4 acc[4][4] = {};  // [mt: 0,1 gamma / 2,3 beta][nt]

    #pragma unroll
    for (int kc = 0; kc < NKC; ++kc) {
        // A fragments from LDS (no VMEM in the k-loop at all)
        bf16x8 af[4];
        #pragma unroll
        for (int mt = 0; mt < 4; ++mt)
            af[mt] = *reinterpret_cast<const bf16x8*>(
                &Alds[(kc * 4 + mt) * 512 + lane * 8]);

        // build zp fragments (MFMA A operand) in registers for this k-chunk
        bf16x8 bfr[4];
        if (kc < 6) {
            const int hf = kc & 1;       // which 32-wide d half
            const int k  = kc >> 1;      // expert index
            #pragma unroll
            for (int nt = 0; nt < 4; ++nt) {
                float p = pv[nt][k];
                #pragma unroll
                for (int j = 0; j < 4; ++j) {
                    bfr[nt][j]     = (bf16)(p * zf[nt][hf][0][j]);
                    bfr[nt][j + 4] = (bf16)(p * zf[nt][hf][1][j]);
                }
            }
        } else {  // kc == 6: bias chunk (kd 192..194 live in q==0 lanes only)
            #pragma unroll
            for (int nt = 0; nt < 4; ++nt) {
                #pragma unroll
                for (int j = 0; j < 8; ++j) bfr[nt][j] = (bf16)0.0f;
                if (q == 0) {
                    bfr[nt][0] = (bf16)pv[nt][0];
                    bfr[nt][1] = (bf16)pv[nt][1];
                    bfr[nt][2] = (bf16)pv[nt][2];
                }
            }
        }
        // SWAPPED operand order: D[row=pixel][col=c]
        #pragma unroll
        for (int mt = 0; mt < 4; ++mt)
            #pragma unroll
            for (int nt = 0; nt < 4; ++nt)
                acc[mt][nt] = __builtin_amdgcn_mfma_f32_16x16x32_bf16(
                    bfr[nt], af[mt], acc[mt][nt], 0, 0, 0);
    }

    // fused FiLM epilogue, fully float4: out = feat*(1+gamma) + beta
    // c = cbase + mt*16 + l15 ; pix = pix0 + nt*16 + q*4 .. +3
    const float* featb = feat + ((size_t)(b * NC + cbase + l15)) * NPIX + pix0 + q * 4;
    float* outb = out + ((size_t)(b * NC + cbase + l15)) * NPIX + pix0 + q * 4;
    #pragma unroll
    for (int mt = 0; mt < 2; ++mt) {
        #pragma unroll
        for (int nt = 0; nt < 4; ++nt) {
            floatx4 f = *reinterpret_cast<const floatx4*>(
                featb + (size_t)mt * 16 * NPIX + nt * 16);
            floatx4 ga = acc[mt][nt];
            floatx4 be = acc[mt + 2][nt];
            floatx4 o;
            #pragma unroll
            for (int j = 0; j < 4; ++j)
                o[j] = f[j] * (1.0f + ga[j]) + be[j];
            *reinterpret_cast<floatx4*>(outb + (size_t)mt * 16 * NPIX + nt * 16) = o;
        }
    }
}

// ---------------------------------------------------------------------------
extern "C" void kernel_launch(void* const* d_in, const int* in_sizes, int n_in,
                              void* d_out, int out_size, void* d_ws, size_t ws_size,
                              hipStream_t stream)
{
    (void)in_sizes; (void)n_in; (void)out_size; (void)ws_size;
    const float* feat = (const float*)d_in[0];
    const float* Z    = (const float*)d_in[1];
    const float* P    = (const float*)d_in[2];
    const float* Wg   = (const float*)d_in[3];
    const float* bg   = (const float*)d_in[4];
    const float* Wb   = (const float*)d_in[5];
    const float* bb   = (const float*)d_in[6];

    float* ZF = (float*)d_ws;                               // 26,214,400 B
    float* PU = ZF + (size_t)NB * NPB * 2 * 64 * 8;         // + 1,228,800 B
    bf16*  Apk = (bf16*)(PU + (size_t)NB * NPB * 3 * 16);   // + 229,376 B
    float* out = (float*)d_out;

    prep_kernel<<<NB * HF + 56, 256, 0, stream>>>(Z, P, Wg, bg, Wb, bb, ZF, PU, Apk);

    dim3 grid(NPIX / 256, 8, NB);
    gemm_film_kernel<<<grid, 256, 0, stream>>>(Apk, ZF, PU, feat, out);
}